// Round 22
// baseline (12541.949 us; speedup 1.0000x reference)
//
#include <hip/hip_runtime.h>
#include <hip/hip_fp16.h>
#include <math.h>

// EchoStateNetwork: B=32, S=4096, I=64, R=1024, O=8, fp32.
// r20 arithmetic (proven 9.58 ms) with the group barrier REPLACED by an
// epoch-stamped dataflow exchange: each rv half2-pair word is stored as
// one atomic b64 (tag=t+1 in hi32, data in lo32) into slab t&1; consumers
// gather r_{t-1} by polling their 4 slab words until tag==t. The gather
// IS the barrier: no drain, no arrive RMW, no counter poll (3 L3 RTs -> 1).
// Safety: store value is data-dependent on gathered loads (program order);
// slab overwrite at t+2 transitively requires every WG's t+1 gather done;
// wrong-epoch reads retry (all races benign); init re-zeroes tags.

#define NS 4096
#define NI 64
#define NR 1024
#define NO 8
#define NB 32
#define NGRP 8
#define GPP 32      // WGs per group
#define CPG 4       // chains per group
#define WROWS 32    // W_res rows per WG
#define NT 512
#define XPAD 68     // padded row stride (272B, 16B-aligned)
#define RSLAB 16384 // u64 per parity slab (32 chains x 512 words)

typedef __fp16 h2 __attribute__((ext_vector_type(2)));
union UH2 { unsigned u; h2 h; };

#define ATSU64(p,v) __hip_atomic_store((p), (v), __ATOMIC_RELAXED, __HIP_MEMORY_SCOPE_AGENT)
#define ATLU64(p)   __hip_atomic_load((p), __ATOMIC_RELAXED, __HIP_MEMORY_SCOPE_AGENT)

static __device__ __forceinline__ h2 u2h(unsigned u) { UH2 t; t.u = u; return t.h; }

static __device__ __forceinline__ float fast_tanh(float x) {
  x = fminf(fmaxf(x, -20.f), 20.f);                    // tanh saturated past +-20
  float e = __builtin_amdgcn_exp2f(x * 2.8853900817779268f);  // e^(2x)
  return (e - 1.0f) * __builtin_amdgcn_rcpf(e + 1.0f);
}

__global__ void init_rbuf_kernel(unsigned long long* rbuf_e) {
  // 32 blocks x 1024 threads zero 2 slabs x 16384 u64 = 256 KB (tags -> 0)
  rbuf_e[(size_t)blockIdx.x * 1024 + threadIdx.x] = 0ull;
}

__global__ __launch_bounds__(NT)
__attribute__((amdgpu_waves_per_eu(2, 2)))
void esn_scan(const float* __restrict__ x, const float* __restrict__ Win,
              const float* __restrict__ Wres, const float* __restrict__ Wout,
              float* __restrict__ out, unsigned long long* __restrict__ rbuf_e)
{
  extern __shared__ float dynpad[];  // 64 KB occupancy shaping (dispatch-reserved)
  const int wg  = blockIdx.x;
  const int g   = wg & 7;    // group
  const int m   = wg >> 3;   // member 0..31
  const int tid = threadIdx.x;
  const int w   = tid >> 6;  // wave 0..7
  const int l   = tid & 63;  // lane

  __shared__ unsigned r_h[CPG][NR / 2];    // 8 KB: r_{t-1} as half2 pairs
  __shared__ float x_lds[3][CPG][XPAD];    // mod-3 ring (272B rows, aligned)
  __shared__ float win_s[WROWS][XPAD];     // 8.7 KB
  __shared__ unsigned woutr_h[NO][NR / 2]; // 16 KB: W_out r-part as half2
  __shared__ float woutx_s[NO][NI];        // 2 KB: W_out x-part fp32

  // never-true guard keeps dynpad referenced
  if (x[0] == 1234.5678f) { dynpad[tid] = 1.f; out[tid] = dynpad[tid ^ 1]; }

  // ---- startup: weights -> fp16 pairs (regs/LDS) ----
  h2 wh[32];  // wh[(r*4+s)*2+p] = W_res[32m+4w+r][4l+256s+2p .. +1]
  {
    const int grow0 = 32 * m + 4 * w;
    #pragma unroll
    for (int r = 0; r < 4; ++r)
      #pragma unroll
      for (int s = 0; s < 4; ++s) {
        float4 t4 = *(const float4*)&Wres[(size_t)(grow0 + r) * NR + 4 * l + 256 * s];
        wh[(r * 4 + s) * 2 + 0] = __builtin_amdgcn_cvt_pkrtz(t4.x, t4.y);
        wh[(r * 4 + s) * 2 + 1] = __builtin_amdgcn_cvt_pkrtz(t4.z, t4.w);
      }
  }
  for (int idx = tid; idx < WROWS * NI; idx += NT) {
    int rr = idx >> 6, ii = idx & 63;
    win_s[rr][ii] = Win[(32 * m + rr) * NI + ii];
  }
  for (int idx = tid; idx < NO * (NR / 2); idx += NT) {
    int o = idx >> 9, p = idx & 511;
    UH2 t; t.h = __builtin_amdgcn_cvt_pkrtz(Wout[o * (NI + NR) + NI + 2 * p],
                                            Wout[o * (NI + NR) + NI + 2 * p + 1]);
    woutr_h[o][p] = t.u;
  }
  if (tid < NO * NI) {
    int o = tid >> 6, ii = tid & 63;
    woutx_s[o][ii] = Wout[o * (NI + NR) + ii];
  }
  if (tid < 256) {  // x[0] into ring slot 0
    const int c = tid >> 6, ii = tid & 63;
    x_lds[0][c][ii] = x[(size_t)(4 * g + c) * NS * NI + ii];
  }
  __syncthreads();

  for (int t = 0; t < NS; ++t) {
    const int par = t & 1, pprev = par ^ 1;

    // ---- Phase L: epoch-tagged gather (issue first attempt) ----
    unsigned long long e0 = 0ull, e1 = 0ull, e2 = 0ull, e3 = 0ull;
    const unsigned long long* rq = rbuf_e + (size_t)pprev * RSLAB
                                 + (size_t)(4 * g) * 512 + tid;
    if (t > 0) {
      e0 = ATLU64(rq);
      e1 = ATLU64(rq + 512);
      e2 = ATLU64(rq + 1024);
      e3 = ATLU64(rq + 1536);
    }

    // ---- pin (overlaps the in-flight gather loads) ----
    // pair p=l&15 (row 4w+(p>>2), chain p&3), chunk l>>4
    float pin;
    {
      const int p = l & 15;
      const int prow = 4 * w + (p >> 2);
      const int pc = p & 3;
      const int cb = (l >> 4) * 16;
      const float* wr = &win_s[prow][cb];
      const float* xr = &x_lds[t % 3][pc][cb];
      float4 a0 = *(const float4*)&wr[0];
      float4 a1 = *(const float4*)&wr[4];
      float4 a2 = *(const float4*)&wr[8];
      float4 a3 = *(const float4*)&wr[12];
      float4 b0 = *(const float4*)&xr[0];
      float4 b1 = *(const float4*)&xr[4];
      float4 b2 = *(const float4*)&xr[8];
      float4 b3 = *(const float4*)&xr[12];
      pin = a0.x * b0.x;
      pin = fmaf(a0.y, b0.y, pin); pin = fmaf(a0.z, b0.z, pin);
      pin = fmaf(a0.w, b0.w, pin);
      pin = fmaf(a1.x, b1.x, pin); pin = fmaf(a1.y, b1.y, pin);
      pin = fmaf(a1.z, b1.z, pin); pin = fmaf(a1.w, b1.w, pin);
      pin = fmaf(a2.x, b2.x, pin); pin = fmaf(a2.y, b2.y, pin);
      pin = fmaf(a2.z, b2.z, pin); pin = fmaf(a2.w, b2.w, pin);
      pin = fmaf(a3.x, b3.x, pin); pin = fmaf(a3.y, b3.y, pin);
      pin = fmaf(a3.z, b3.z, pin); pin = fmaf(a3.w, b3.w, pin);
      pin += __shfl_xor(pin, 16);
      pin += __shfl_xor(pin, 32);
    }

    // ---- poll stale words until tag == t (the gather IS the barrier) ----
    if (t > 0) {
      const unsigned tg = (unsigned)t;
      for (;;) {
        const bool s0 = (unsigned)(e0 >> 32) != tg;
        const bool s1 = (unsigned)(e1 >> 32) != tg;
        const bool s2 = (unsigned)(e2 >> 32) != tg;
        const bool s3 = (unsigned)(e3 >> 32) != tg;
        if (!(s0 | s1 | s2 | s3)) break;
        if (s0) e0 = ATLU64(rq);
        if (s1) e1 = ATLU64(rq + 512);
        if (s2) e2 = ATLU64(rq + 1024);
        if (s3) e3 = ATLU64(rq + 1536);
      }
    }

    // ---- land gather into LDS ----
    r_h[0][tid] = (unsigned)e0; r_h[1][tid] = (unsigned)e1;
    r_h[2][tid] = (unsigned)e2; r_h[3][tid] = (unsigned)e3;
    __syncthreads();

    // ---- dot: acc[r][c] via v_dot2_f32_f16 (16 cols/thread) ----
    float acc[4][4];
    #pragma unroll
    for (int r = 0; r < 4; ++r)
      #pragma unroll
      for (int c = 0; c < 4; ++c) acc[r][c] = 0.f;
    #pragma unroll
    for (int s = 0; s < 4; ++s) {
      uint2 q0 = *(const uint2*)&r_h[0][2 * l + 128 * s];
      uint2 q1 = *(const uint2*)&r_h[1][2 * l + 128 * s];
      uint2 q2 = *(const uint2*)&r_h[2][2 * l + 128 * s];
      uint2 q3 = *(const uint2*)&r_h[3][2 * l + 128 * s];
      #pragma unroll
      for (int r = 0; r < 4; ++r) {
        const h2 wa = wh[(r * 4 + s) * 2 + 0];
        const h2 wb = wh[(r * 4 + s) * 2 + 1];
        acc[r][0] = __builtin_amdgcn_fdot2(wa, u2h(q0.x), acc[r][0], false);
        acc[r][0] = __builtin_amdgcn_fdot2(wb, u2h(q0.y), acc[r][0], false);
        acc[r][1] = __builtin_amdgcn_fdot2(wa, u2h(q1.x), acc[r][1], false);
        acc[r][1] = __builtin_amdgcn_fdot2(wb, u2h(q1.y), acc[r][1], false);
        acc[r][2] = __builtin_amdgcn_fdot2(wa, u2h(q2.x), acc[r][2], false);
        acc[r][2] = __builtin_amdgcn_fdot2(wb, u2h(q2.y), acc[r][2], false);
        acc[r][3] = __builtin_amdgcn_fdot2(wa, u2h(q3.x), acc[r][3], false);
        acc[r][3] = __builtin_amdgcn_fdot2(wb, u2h(q3.y), acc[r][3], false);
      }
    }

    // ---- paired butterfly: 16 sums across 64 lanes ----
    float v[16];
    #pragma unroll
    for (int k = 0; k < 16; ++k) v[k] = acc[k >> 2][k & 3];
    #pragma unroll
    for (int lev = 0; lev < 4; ++lev) {
      const int d = 1 << lev;
      const int n = 16 >> lev;
      #pragma unroll
      for (int i = 0; i < n / 2; ++i) {
        float a  = v[2 * i]     + __shfl_xor(v[2 * i],     d);
        float bb = v[2 * i + 1] + __shfl_xor(v[2 * i + 1], d);
        v[i] = (l & d) ? bb : a;
      }
    }
    float dsum = v[0];
    dsum += __shfl_xor(dsum, 16);
    dsum += __shfl_xor(dsum, 32);

    // ---- finalize: fast tanh + pack + single tagged b64 store/word ----
    {
      float rv = fast_tanh(dsum + pin);      // lane l: value for pair l&15
      float rvo = __shfl_xor(rv, 4);         // partner row (r^1), same chain
      UH2 hp; hp.h = __builtin_amdgcn_cvt_pkrtz(rv, rvo);  // (r,r+1) packed
      if (l < 16 && ((l >> 2) & 1) == 0) {   // lanes {0..3, 8..11}: r even
        const int r = l >> 2, c = l & 3;
        const int word = 16 * m + 2 * w + (r >> 1);
        const unsigned long long pkt =
          (((unsigned long long)(unsigned)(t + 1)) << 32) | (unsigned long long)hp.u;
        ATSU64(rbuf_e + (size_t)par * RSLAB + (size_t)(4 * g + c) * 512 + word, pkt);
      }
    }

    // ---- shadow work (no barrier to wait on; just prep next step) ----
    if (t + 1 < NS && tid < 256) {
      const int c = tid >> 6, ii = tid & 63;
      x_lds[(t + 1) % 3][c][ii] = x[((size_t)(4 * g + c) * NS + (t + 1)) * NI + ii];
    }
    if (t > 0 && m == ((t - 1) & 31)) {   // rotating local output reduction
      const int grp = tid >> 4;   // 0..31 -> (c,o)
      const int j   = tid & 15;
      const int c   = grp >> 3, o = grp & 7;
      float s = 0.f;
      #pragma unroll
      for (int k = 0; k < 16; ++k) {
        uint2 rr = *(const uint2*)&r_h[c][32 * k + 2 * j];
        uint2 ww = *(const uint2*)&woutr_h[o][32 * k + 2 * j];
        s = __builtin_amdgcn_fdot2(u2h(rr.x), u2h(ww.x), s, false);
        s = __builtin_amdgcn_fdot2(u2h(rr.y), u2h(ww.y), s, false);
      }
      #pragma unroll
      for (int e = 0; e < 4; ++e)
        s = fmaf(woutx_s[o][4 * j + e], x_lds[(t + 2) % 3][c][4 * j + e], s);
      s += __shfl_xor(s, 1); s += __shfl_xor(s, 2);
      s += __shfl_xor(s, 4); s += __shfl_xor(s, 8);
      if (j == 0) out[((size_t)(4 * g + c) * NS + (t - 1)) * NO + o] = s;
    }

    __syncthreads();   // protect r_h / x_lds for next iteration
  }

  // ---- final output row t = NS-1 (one WG per group; tag NS poll) ----
  if (m == 31) {
    const int fpar = (NS - 1) & 1;
    const unsigned long long* rq = rbuf_e + (size_t)fpar * RSLAB
                                 + (size_t)(4 * g) * 512 + tid;
    unsigned long long e0 = ATLU64(rq),        e1 = ATLU64(rq + 512);
    unsigned long long e2 = ATLU64(rq + 1024), e3 = ATLU64(rq + 1536);
    const unsigned tg = (unsigned)NS;
    for (;;) {
      const bool s0 = (unsigned)(e0 >> 32) != tg;
      const bool s1 = (unsigned)(e1 >> 32) != tg;
      const bool s2 = (unsigned)(e2 >> 32) != tg;
      const bool s3 = (unsigned)(e3 >> 32) != tg;
      if (!(s0 | s1 | s2 | s3)) break;
      if (s0) e0 = ATLU64(rq);
      if (s1) e1 = ATLU64(rq + 512);
      if (s2) e2 = ATLU64(rq + 1024);
      if (s3) e3 = ATLU64(rq + 1536);
    }
    r_h[0][tid] = (unsigned)e0; r_h[1][tid] = (unsigned)e1;
    r_h[2][tid] = (unsigned)e2; r_h[3][tid] = (unsigned)e3;
    __syncthreads();
    const int grp = tid >> 4;
    const int j   = tid & 15;
    const int c   = grp >> 3, o = grp & 7;
    float s = 0.f;
    #pragma unroll
    for (int k = 0; k < 16; ++k) {
      uint2 rr = *(const uint2*)&r_h[c][32 * k + 2 * j];
      uint2 ww = *(const uint2*)&woutr_h[o][32 * k + 2 * j];
      s = __builtin_amdgcn_fdot2(u2h(rr.x), u2h(ww.x), s, false);
      s = __builtin_amdgcn_fdot2(u2h(rr.y), u2h(ww.y), s, false);
    }
    #pragma unroll
    for (int e = 0; e < 4; ++e)
      s = fmaf(woutx_s[o][4 * j + e], x_lds[(NS - 1) % 3][c][4 * j + e], s);
    s += __shfl_xor(s, 1); s += __shfl_xor(s, 2);
    s += __shfl_xor(s, 4); s += __shfl_xor(s, 8);
    if (j == 0) out[((size_t)(4 * g + c) * NS + (NS - 1)) * NO + o] = s;
  }
}

extern "C" void kernel_launch(void* const* d_in, const int* in_sizes, int n_in,
                              void* d_out, int out_size, void* d_ws, size_t ws_size,
                              hipStream_t stream) {
  const float* x    = (const float*)d_in[0];
  const float* Win  = (const float*)d_in[1];
  const float* Wres = (const float*)d_in[2];
  const float* Wout = (const float*)d_in[3];
  float* out = (float*)d_out;

  unsigned long long* rbuf_e = (unsigned long long*)d_ws;  // 2 slabs x 128 KB

  hipLaunchKernelGGL(init_rbuf_kernel, dim3(32), dim3(1024), 0, stream, rbuf_e);
  hipLaunchKernelGGL(esn_scan, dim3(256), dim3(NT), 64 * 1024, stream,
                     x, Win, Wres, Wout, out, rbuf_e);
}

// Round 23
// 11033.607 us; speedup vs baseline: 1.1367x; 1.1367x over previous
//
#include <hip/hip_runtime.h>
#include <hip/hip_fp16.h>
#include <math.h>

// EchoStateNetwork: B=32, S=4096, I=64, R=1024, O=8, fp32.
// r20 (proven 9.58 ms) + two minimal protocol deltas:
//  (1) arrive rebalanced 4x8 -> 8x4: line = m&7, 4 serialized RMWs deep
//      (halves last-arriver RMW depth); poll = 8 pipelined loads, lane 0.
//  (2) x[t+1] prefetch moved to wave 7 (64 lanes x float4): its LDS-store
//      stall overlaps the poll in a parallel wave instead of delaying the
//      polling lane (r20 had tids 0-255 incl. the poller stall on x).
// Everything else byte-identical to r20: fp16 rbuf chain-major transport,
// dense 4-load gather, hoisted pin, fdot2 dot, fast_tanh, shadow reducer.

#define NS 4096
#define NI 64
#define NR 1024
#define NO 8
#define NB 32
#define NGRP 8
#define GPP 32      // WGs per group
#define CPG 4       // chains per group
#define WROWS 32    // W_res rows per WG
#define NT 512
#define XPAD 68     // padded row stride (272B, 16B-aligned)

typedef __fp16 h2 __attribute__((ext_vector_type(2)));
union UH2 { unsigned u; h2 h; };

#define ATSU(p,v) __hip_atomic_store((p), (v), __ATOMIC_RELAXED, __HIP_MEMORY_SCOPE_AGENT)
#define ATLU(p)   __hip_atomic_load((p), __ATOMIC_RELAXED, __HIP_MEMORY_SCOPE_AGENT)
#define ATAU(p,v) __hip_atomic_fetch_add((p), (v), __ATOMIC_RELAXED, __HIP_MEMORY_SCOPE_AGENT)

static __device__ __forceinline__ h2 u2h(unsigned u) { UH2 t; t.u = u; return t.h; }

static __device__ __forceinline__ float fast_tanh(float x) {
  x = fminf(fmaxf(x, -20.f), 20.f);                    // tanh saturated past +-20
  float e = __builtin_amdgcn_exp2f(x * 2.8853900817779268f);  // e^(2x)
  return (e - 1.0f) * __builtin_amdgcn_rcpf(e + 1.0f);
}

__global__ void init_cnt_kernel(unsigned int* cnt) {
  const int t = threadIdx.x;   // zero 16 KB: 8 groups x 8 lines x 64 dwords
  cnt[t] = 0u; cnt[t + 1024] = 0u; cnt[t + 2048] = 0u; cnt[t + 3072] = 0u;
}

__global__ __launch_bounds__(NT)
__attribute__((amdgpu_waves_per_eu(2, 2)))
void esn_scan(const float* __restrict__ x, const float* __restrict__ Win,
              const float* __restrict__ Wres, const float* __restrict__ Wout,
              float* __restrict__ out, unsigned int* __restrict__ cnt,
              unsigned int* __restrict__ rbuf_h)
{
  extern __shared__ float dynpad[];  // 64 KB occupancy shaping (dispatch-reserved)
  const int wg  = blockIdx.x;
  const int g   = wg & 7;    // group
  const int m   = wg >> 3;   // member 0..31
  const int tid = threadIdx.x;
  const int w   = tid >> 6;  // wave 0..7
  const int l   = tid & 63;  // lane

  __shared__ unsigned r_h[CPG][NR / 2];    // 8 KB: r_{t-1} as half2 pairs
  __shared__ float x_lds[3][CPG][XPAD];    // mod-3 ring (272B rows, aligned)
  __shared__ float win_s[WROWS][XPAD];     // 8.7 KB
  __shared__ unsigned woutr_h[NO][NR / 2]; // 16 KB: W_out r-part as half2
  __shared__ float woutx_s[NO][NI];        // 2 KB: W_out x-part fp32

  // never-true guard keeps dynpad referenced
  if (x[0] == 1234.5678f) { dynpad[tid] = 1.f; out[tid] = dynpad[tid ^ 1]; }

  // ---- startup: weights -> fp16 pairs (regs/LDS) ----
  h2 wh[32];  // wh[(r*4+s)*2+p] = W_res[32m+4w+r][4l+256s+2p .. +1]
  {
    const int grow0 = 32 * m + 4 * w;
    #pragma unroll
    for (int r = 0; r < 4; ++r)
      #pragma unroll
      for (int s = 0; s < 4; ++s) {
        float4 t4 = *(const float4*)&Wres[(size_t)(grow0 + r) * NR + 4 * l + 256 * s];
        wh[(r * 4 + s) * 2 + 0] = __builtin_amdgcn_cvt_pkrtz(t4.x, t4.y);
        wh[(r * 4 + s) * 2 + 1] = __builtin_amdgcn_cvt_pkrtz(t4.z, t4.w);
      }
  }
  for (int idx = tid; idx < WROWS * NI; idx += NT) {
    int rr = idx >> 6, ii = idx & 63;
    win_s[rr][ii] = Win[(32 * m + rr) * NI + ii];
  }
  for (int idx = tid; idx < NO * (NR / 2); idx += NT) {
    int o = idx >> 9, p = idx & 511;
    UH2 t; t.h = __builtin_amdgcn_cvt_pkrtz(Wout[o * (NI + NR) + NI + 2 * p],
                                            Wout[o * (NI + NR) + NI + 2 * p + 1]);
    woutr_h[o][p] = t.u;
  }
  if (tid < NO * NI) {
    int o = tid >> 6, ii = tid & 63;
    woutx_s[o][ii] = Wout[o * (NI + NR) + ii];
  }
  if (tid < 256) {  // x[0] into ring slot 0
    const int c = tid >> 6, ii = tid & 63;
    x_lds[0][c][ii] = x[(size_t)(4 * g + c) * NS * NI + ii];
  }
  __syncthreads();

  unsigned int* bcp = cnt + (g * 8 + (m & 7)) * 64;  // my arrive line (4 RMWs deep)
  unsigned int* pol = cnt + g * 8 * 64;              // poll base (8 lines)

  for (int t = 0; t < NS; ++t) {
    const int par = t & 1, pprev = par ^ 1;

    // ---- Phase L: gather r_{t-1} (4 dense agent b32 loads, chain-major) ----
    unsigned uv0, uv1, uv2, uv3;
    if (t > 0) {
      const unsigned* rq = rbuf_h + (size_t)pprev * NB * (NR / 2)
                                  + (size_t)(4 * g) * (NR / 2);
      uv0 = ATLU(rq + tid);
      uv1 = ATLU(rq + 512 + tid);
      uv2 = ATLU(rq + 1024 + tid);
      uv3 = ATLU(rq + 1536 + tid);
    } else {
      uv0 = uv1 = uv2 = uv3 = 0u;
    }

    // ---- pin (hoisted; rides under the gather round trip) ----
    // pair p=l&15 (row 4w+(p>>2), chain p&3), chunk l>>4
    float pin;
    {
      const int p = l & 15;
      const int prow = 4 * w + (p >> 2);
      const int pc = p & 3;
      const int cb = (l >> 4) * 16;
      const float* wr = &win_s[prow][cb];
      const float* xr = &x_lds[t % 3][pc][cb];
      float4 a0 = *(const float4*)&wr[0];
      float4 a1 = *(const float4*)&wr[4];
      float4 a2 = *(const float4*)&wr[8];
      float4 a3 = *(const float4*)&wr[12];
      float4 b0 = *(const float4*)&xr[0];
      float4 b1 = *(const float4*)&xr[4];
      float4 b2 = *(const float4*)&xr[8];
      float4 b3 = *(const float4*)&xr[12];
      pin = a0.x * b0.x;
      pin = fmaf(a0.y, b0.y, pin); pin = fmaf(a0.z, b0.z, pin);
      pin = fmaf(a0.w, b0.w, pin);
      pin = fmaf(a1.x, b1.x, pin); pin = fmaf(a1.y, b1.y, pin);
      pin = fmaf(a1.z, b1.z, pin); pin = fmaf(a1.w, b1.w, pin);
      pin = fmaf(a2.x, b2.x, pin); pin = fmaf(a2.y, b2.y, pin);
      pin = fmaf(a2.z, b2.z, pin); pin = fmaf(a2.w, b2.w, pin);
      pin = fmaf(a3.x, b3.x, pin); pin = fmaf(a3.y, b3.y, pin);
      pin = fmaf(a3.z, b3.z, pin); pin = fmaf(a3.w, b3.w, pin);
      pin += __shfl_xor(pin, 16);
      pin += __shfl_xor(pin, 32);
    }

    // ---- land gather into LDS ----
    r_h[0][tid] = uv0; r_h[1][tid] = uv1;
    r_h[2][tid] = uv2; r_h[3][tid] = uv3;
    __syncthreads();

    // ---- dot: acc[r][c] via v_dot2_f32_f16 (16 cols/thread) ----
    float acc[4][4];
    #pragma unroll
    for (int r = 0; r < 4; ++r)
      #pragma unroll
      for (int c = 0; c < 4; ++c) acc[r][c] = 0.f;
    #pragma unroll
    for (int s = 0; s < 4; ++s) {
      uint2 q0 = *(const uint2*)&r_h[0][2 * l + 128 * s];
      uint2 q1 = *(const uint2*)&r_h[1][2 * l + 128 * s];
      uint2 q2 = *(const uint2*)&r_h[2][2 * l + 128 * s];
      uint2 q3 = *(const uint2*)&r_h[3][2 * l + 128 * s];
      #pragma unroll
      for (int r = 0; r < 4; ++r) {
        const h2 wa = wh[(r * 4 + s) * 2 + 0];
        const h2 wb = wh[(r * 4 + s) * 2 + 1];
        acc[r][0] = __builtin_amdgcn_fdot2(wa, u2h(q0.x), acc[r][0], false);
        acc[r][0] = __builtin_amdgcn_fdot2(wb, u2h(q0.y), acc[r][0], false);
        acc[r][1] = __builtin_amdgcn_fdot2(wa, u2h(q1.x), acc[r][1], false);
        acc[r][1] = __builtin_amdgcn_fdot2(wb, u2h(q1.y), acc[r][1], false);
        acc[r][2] = __builtin_amdgcn_fdot2(wa, u2h(q2.x), acc[r][2], false);
        acc[r][2] = __builtin_amdgcn_fdot2(wb, u2h(q2.y), acc[r][2], false);
        acc[r][3] = __builtin_amdgcn_fdot2(wa, u2h(q3.x), acc[r][3], false);
        acc[r][3] = __builtin_amdgcn_fdot2(wb, u2h(q3.y), acc[r][3], false);
      }
    }

    // ---- paired butterfly: 16 sums across 64 lanes ----
    float v[16];
    #pragma unroll
    for (int k = 0; k < 16; ++k) v[k] = acc[k >> 2][k & 3];
    #pragma unroll
    for (int lev = 0; lev < 4; ++lev) {
      const int d = 1 << lev;
      const int n = 16 >> lev;
      #pragma unroll
      for (int i = 0; i < n / 2; ++i) {
        float a  = v[2 * i]     + __shfl_xor(v[2 * i],     d);
        float bb = v[2 * i + 1] + __shfl_xor(v[2 * i + 1], d);
        v[i] = (l & d) ? bb : a;
      }
    }
    float dsum = v[0];
    dsum += __shfl_xor(dsum, 16);
    dsum += __shfl_xor(dsum, 32);

    // ---- finalize: fast tanh + pack half2 + agent store (chain-major) ----
    {
      float rv = fast_tanh(dsum + pin);      // lane l: value for pair l&15
      float rvo = __shfl_xor(rv, 4);         // partner row (r^1), same chain
      if (l < 16 && ((l >> 2) & 1) == 0) {   // r even: pack (row r, row r+1)
        const int r = l >> 2, c = l & 3;
        UH2 hp; hp.h = __builtin_amdgcn_cvt_pkrtz(rv, rvo);
        const int pair = 16 * m + 2 * w + (r >> 1);
        ATSU(rbuf_h + (size_t)par * NB * (NR / 2)
                    + (size_t)(4 * g + c) * (NR / 2) + pair, hp.u);
      }
    }

    // ---- arrive (early): __syncthreads drains vmcnt(0) first ----
    __syncthreads();
    if (tid == 0) ATAU(bcp, 1u);

    // ---- shadow work while the group converges ----
    if (t + 1 < NS && w == 7) {   // wave 7 only: float4 x[t+1] prefetch
      const int q = l;            // 0..63
      const int c = q >> 4, qq = q & 15;
      float4 xv = *(const float4*)&x[((size_t)(4 * g + c) * NS + (t + 1)) * NI + 4 * qq];
      *(float4*)&x_lds[(t + 1) % 3][c][4 * qq] = xv;
    }
    if (t > 0 && m == ((t - 1) & 31)) {   // rotating local output reduction
      const int grp = tid >> 4;   // 0..31 -> (c,o)
      const int j   = tid & 15;
      const int c   = grp >> 3, o = grp & 7;
      float s = 0.f;
      #pragma unroll
      for (int k = 0; k < 16; ++k) {
        uint2 rr = *(const uint2*)&r_h[c][32 * k + 2 * j];
        uint2 ww = *(const uint2*)&woutr_h[o][32 * k + 2 * j];
        s = __builtin_amdgcn_fdot2(u2h(rr.x), u2h(ww.x), s, false);
        s = __builtin_amdgcn_fdot2(u2h(rr.y), u2h(ww.y), s, false);
      }
      #pragma unroll
      for (int e = 0; e < 4; ++e)
        s = fmaf(woutx_s[o][4 * j + e], x_lds[(t + 2) % 3][c][4 * j + e], s);
      s += __shfl_xor(s, 1); s += __shfl_xor(s, 2);
      s += __shfl_xor(s, 4); s += __shfl_xor(s, 8);
      if (j == 0) out[((size_t)(4 * g + c) * NS + (t - 1)) * NO + o] = s;
    }

    // ---- wait (late): single lane polls 8 lines (pipelined, ~1 RT) ----
    if (tid == 0) {
      const unsigned tg = 4u * (unsigned)(t + 1);
      for (;;) {
        unsigned u0 = ATLU(pol);
        unsigned u1 = ATLU(pol + 64);
        unsigned u2 = ATLU(pol + 128);
        unsigned u3 = ATLU(pol + 192);
        unsigned u4 = ATLU(pol + 256);
        unsigned u5 = ATLU(pol + 320);
        unsigned u6 = ATLU(pol + 384);
        unsigned u7 = ATLU(pol + 448);
        if (u0 >= tg && u1 >= tg && u2 >= tg && u3 >= tg &&
            u4 >= tg && u5 >= tg && u6 >= tg && u7 >= tg) break;
      }
    }
    __syncthreads();
  }

  // ---- final output row t = NS-1 (one WG per group; r from rbuf_h) ----
  if (m == 31) {
    const int fpar = (NS - 1) & 1;
    const unsigned* rq = rbuf_h + (size_t)fpar * NB * (NR / 2)
                                + (size_t)(4 * g) * (NR / 2);
    r_h[0][tid] = ATLU(rq + tid);
    r_h[1][tid] = ATLU(rq + 512 + tid);
    r_h[2][tid] = ATLU(rq + 1024 + tid);
    r_h[3][tid] = ATLU(rq + 1536 + tid);
    __syncthreads();
    const int grp = tid >> 4;
    const int j   = tid & 15;
    const int c   = grp >> 3, o = grp & 7;
    float s = 0.f;
    #pragma unroll
    for (int k = 0; k < 16; ++k) {
      uint2 rr = *(const uint2*)&r_h[c][32 * k + 2 * j];
      uint2 ww = *(const uint2*)&woutr_h[o][32 * k + 2 * j];
      s = __builtin_amdgcn_fdot2(u2h(rr.x), u2h(ww.x), s, false);
      s = __builtin_amdgcn_fdot2(u2h(rr.y), u2h(ww.y), s, false);
    }
    #pragma unroll
    for (int e = 0; e < 4; ++e)
      s = fmaf(woutx_s[o][4 * j + e], x_lds[(NS - 1) % 3][c][4 * j + e], s);
    s += __shfl_xor(s, 1); s += __shfl_xor(s, 2);
    s += __shfl_xor(s, 4); s += __shfl_xor(s, 8);
    if (j == 0) out[((size_t)(4 * g + c) * NS + (NS - 1)) * NO + o] = s;
  }
}

extern "C" void kernel_launch(void* const* d_in, const int* in_sizes, int n_in,
                              void* d_out, int out_size, void* d_ws, size_t ws_size,
                              hipStream_t stream) {
  const float* x    = (const float*)d_in[0];
  const float* Win  = (const float*)d_in[1];
  const float* Wres = (const float*)d_in[2];
  const float* Wout = (const float*)d_in[3];
  float* out = (float*)d_out;

  char* ws = (char*)d_ws;
  unsigned int* cnt = (unsigned int*)ws;               // 16 KB: 8 groups x 8 lines
  unsigned int* rbuf_h = (unsigned int*)(ws + 16384);  // 2*32*512*4 = 128 KB

  hipLaunchKernelGGL(init_cnt_kernel, dim3(1), dim3(1024), 0, stream, cnt);
  hipLaunchKernelGGL(esn_scan, dim3(256), dim3(NT), 64 * 1024, stream,
                     x, Win, Wres, Wout, out, cnt, rbuf_h);
}

// Round 24
// 9558.253 us; speedup vs baseline: 1.3122x; 1.1544x over previous
//
#include <hip/hip_runtime.h>
#include <hip/hip_fp16.h>
#include <math.h>

// EchoStateNetwork: B=32, S=4096, I=64, R=1024, O=8, fp32.
// FINAL: exact round-20 kernel (session best, 9.58 ms, absmax 0.015625).
// Structure: 8 groups x 32 WGs (grid=256, 1 WG/CU via 64KB dynamic LDS),
// 4 chains/group, 32 W_res rows/WG as fp16 half2 in 32 VGPRs, fdot2 dot,
// fp16 half2 rbuf transport (RELAXED agent atomics, chain-major, dense
// coalesced gather), pin hoisted under the gather L3 round trip,
// fast_tanh, arrive-early (4-line RMW) / wait-late (single-lane 4-load
// poll) barrier with shadow x-prefetch + rotating local output reduction.
// Protocol variants r19/r21/r22/r23 all regressed -> this geometry is the
// practical floor for agent-scope cross-CU exchange on gfx950.

#define NS 4096
#define NI 64
#define NR 1024
#define NO 8
#define NB 32
#define NGRP 8
#define GPP 32      // WGs per group
#define CPG 4       // chains per group
#define WROWS 32    // W_res rows per WG
#define NT 512
#define XPAD 68     // padded row stride (272B, 16B-aligned)

typedef __fp16 h2 __attribute__((ext_vector_type(2)));
union UH2 { unsigned u; h2 h; };

#define ATSU(p,v) __hip_atomic_store((p), (v), __ATOMIC_RELAXED, __HIP_MEMORY_SCOPE_AGENT)
#define ATLU(p)   __hip_atomic_load((p), __ATOMIC_RELAXED, __HIP_MEMORY_SCOPE_AGENT)
#define ATAU(p,v) __hip_atomic_fetch_add((p), (v), __ATOMIC_RELAXED, __HIP_MEMORY_SCOPE_AGENT)

static __device__ __forceinline__ h2 u2h(unsigned u) { UH2 t; t.u = u; return t.h; }

static __device__ __forceinline__ float fast_tanh(float x) {
  x = fminf(fmaxf(x, -20.f), 20.f);                    // tanh saturated past +-20
  float e = __builtin_amdgcn_exp2f(x * 2.8853900817779268f);  // e^(2x)
  return (e - 1.0f) * __builtin_amdgcn_rcpf(e + 1.0f);
}

__global__ void init_cnt_kernel(unsigned int* cnt) {
  cnt[threadIdx.x] = 0u;           // zero 8 KB: 8 groups x 4 lines x 64 dwords
  cnt[threadIdx.x + 1024] = 0u;
}

__global__ __launch_bounds__(NT)
__attribute__((amdgpu_waves_per_eu(2, 2)))
void esn_scan(const float* __restrict__ x, const float* __restrict__ Win,
              const float* __restrict__ Wres, const float* __restrict__ Wout,
              float* __restrict__ out, unsigned int* __restrict__ cnt,
              unsigned int* __restrict__ rbuf_h)
{
  extern __shared__ float dynpad[];  // 64 KB occupancy shaping (dispatch-reserved)
  const int wg  = blockIdx.x;
  const int g   = wg & 7;    // group
  const int m   = wg >> 3;   // member 0..31
  const int tid = threadIdx.x;
  const int w   = tid >> 6;  // wave 0..7
  const int l   = tid & 63;  // lane

  __shared__ unsigned r_h[CPG][NR / 2];    // 8 KB: r_{t-1} as half2 pairs
  __shared__ float x_lds[3][CPG][XPAD];    // mod-3 ring (272B rows, aligned)
  __shared__ float win_s[WROWS][XPAD];     // 8.7 KB
  __shared__ unsigned woutr_h[NO][NR / 2]; // 16 KB: W_out r-part as half2
  __shared__ float woutx_s[NO][NI];        // 2 KB: W_out x-part fp32

  // never-true guard keeps dynpad referenced
  if (x[0] == 1234.5678f) { dynpad[tid] = 1.f; out[tid] = dynpad[tid ^ 1]; }

  // ---- startup: weights -> fp16 pairs (regs/LDS) ----
  h2 wh[32];  // wh[(r*4+s)*2+p] = W_res[32m+4w+r][4l+256s+2p .. +1]
  {
    const int grow0 = 32 * m + 4 * w;
    #pragma unroll
    for (int r = 0; r < 4; ++r)
      #pragma unroll
      for (int s = 0; s < 4; ++s) {
        float4 t4 = *(const float4*)&Wres[(size_t)(grow0 + r) * NR + 4 * l + 256 * s];
        wh[(r * 4 + s) * 2 + 0] = __builtin_amdgcn_cvt_pkrtz(t4.x, t4.y);
        wh[(r * 4 + s) * 2 + 1] = __builtin_amdgcn_cvt_pkrtz(t4.z, t4.w);
      }
  }
  for (int idx = tid; idx < WROWS * NI; idx += NT) {
    int rr = idx >> 6, ii = idx & 63;
    win_s[rr][ii] = Win[(32 * m + rr) * NI + ii];
  }
  for (int idx = tid; idx < NO * (NR / 2); idx += NT) {
    int o = idx >> 9, p = idx & 511;
    UH2 t; t.h = __builtin_amdgcn_cvt_pkrtz(Wout[o * (NI + NR) + NI + 2 * p],
                                            Wout[o * (NI + NR) + NI + 2 * p + 1]);
    woutr_h[o][p] = t.u;
  }
  if (tid < NO * NI) {
    int o = tid >> 6, ii = tid & 63;
    woutx_s[o][ii] = Wout[o * (NI + NR) + ii];
  }
  if (tid < 256) {  // x[0] into ring slot 0
    const int c = tid >> 6, ii = tid & 63;
    x_lds[0][c][ii] = x[(size_t)(4 * g + c) * NS * NI + ii];
  }
  __syncthreads();

  unsigned int* bcp = cnt + (g * 4 + (m & 3)) * 64;  // my arrive line
  unsigned int* pol = cnt + g * 4 * 64;              // poll base (4 lines)

  for (int t = 0; t < NS; ++t) {
    const int par = t & 1, pprev = par ^ 1;

    // ---- Phase L: gather r_{t-1} (4 dense agent b32 loads, chain-major) ----
    unsigned uv0, uv1, uv2, uv3;
    if (t > 0) {
      const unsigned* rq = rbuf_h + (size_t)pprev * NB * (NR / 2)
                                  + (size_t)(4 * g) * (NR / 2);
      uv0 = ATLU(rq + tid);
      uv1 = ATLU(rq + 512 + tid);
      uv2 = ATLU(rq + 1024 + tid);
      uv3 = ATLU(rq + 1536 + tid);
    } else {
      uv0 = uv1 = uv2 = uv3 = 0u;
    }

    // ---- pin (hoisted; rides under the gather round trip) ----
    // pair p=l&15 (row 4w+(p>>2), chain p&3), chunk l>>4
    float pin;
    {
      const int p = l & 15;
      const int prow = 4 * w + (p >> 2);
      const int pc = p & 3;
      const int cb = (l >> 4) * 16;
      const float* wr = &win_s[prow][cb];
      const float* xr = &x_lds[t % 3][pc][cb];
      float4 a0 = *(const float4*)&wr[0];
      float4 a1 = *(const float4*)&wr[4];
      float4 a2 = *(const float4*)&wr[8];
      float4 a3 = *(const float4*)&wr[12];
      float4 b0 = *(const float4*)&xr[0];
      float4 b1 = *(const float4*)&xr[4];
      float4 b2 = *(const float4*)&xr[8];
      float4 b3 = *(const float4*)&xr[12];
      pin = a0.x * b0.x;
      pin = fmaf(a0.y, b0.y, pin); pin = fmaf(a0.z, b0.z, pin);
      pin = fmaf(a0.w, b0.w, pin);
      pin = fmaf(a1.x, b1.x, pin); pin = fmaf(a1.y, b1.y, pin);
      pin = fmaf(a1.z, b1.z, pin); pin = fmaf(a1.w, b1.w, pin);
      pin = fmaf(a2.x, b2.x, pin); pin = fmaf(a2.y, b2.y, pin);
      pin = fmaf(a2.z, b2.z, pin); pin = fmaf(a2.w, b2.w, pin);
      pin = fmaf(a3.x, b3.x, pin); pin = fmaf(a3.y, b3.y, pin);
      pin = fmaf(a3.z, b3.z, pin); pin = fmaf(a3.w, b3.w, pin);
      pin += __shfl_xor(pin, 16);
      pin += __shfl_xor(pin, 32);
    }

    // ---- land gather into LDS ----
    r_h[0][tid] = uv0; r_h[1][tid] = uv1;
    r_h[2][tid] = uv2; r_h[3][tid] = uv3;
    __syncthreads();

    // ---- dot: acc[r][c] via v_dot2_f32_f16 (16 cols/thread) ----
    float acc[4][4];
    #pragma unroll
    for (int r = 0; r < 4; ++r)
      #pragma unroll
      for (int c = 0; c < 4; ++c) acc[r][c] = 0.f;
    #pragma unroll
    for (int s = 0; s < 4; ++s) {
      uint2 q0 = *(const uint2*)&r_h[0][2 * l + 128 * s];
      uint2 q1 = *(const uint2*)&r_h[1][2 * l + 128 * s];
      uint2 q2 = *(const uint2*)&r_h[2][2 * l + 128 * s];
      uint2 q3 = *(const uint2*)&r_h[3][2 * l + 128 * s];
      #pragma unroll
      for (int r = 0; r < 4; ++r) {
        const h2 wa = wh[(r * 4 + s) * 2 + 0];
        const h2 wb = wh[(r * 4 + s) * 2 + 1];
        acc[r][0] = __builtin_amdgcn_fdot2(wa, u2h(q0.x), acc[r][0], false);
        acc[r][0] = __builtin_amdgcn_fdot2(wb, u2h(q0.y), acc[r][0], false);
        acc[r][1] = __builtin_amdgcn_fdot2(wa, u2h(q1.x), acc[r][1], false);
        acc[r][1] = __builtin_amdgcn_fdot2(wb, u2h(q1.y), acc[r][1], false);
        acc[r][2] = __builtin_amdgcn_fdot2(wa, u2h(q2.x), acc[r][2], false);
        acc[r][2] = __builtin_amdgcn_fdot2(wb, u2h(q2.y), acc[r][2], false);
        acc[r][3] = __builtin_amdgcn_fdot2(wa, u2h(q3.x), acc[r][3], false);
        acc[r][3] = __builtin_amdgcn_fdot2(wb, u2h(q3.y), acc[r][3], false);
      }
    }

    // ---- paired butterfly: 16 sums across 64 lanes ----
    float v[16];
    #pragma unroll
    for (int k = 0; k < 16; ++k) v[k] = acc[k >> 2][k & 3];
    #pragma unroll
    for (int lev = 0; lev < 4; ++lev) {
      const int d = 1 << lev;
      const int n = 16 >> lev;
      #pragma unroll
      for (int i = 0; i < n / 2; ++i) {
        float a  = v[2 * i]     + __shfl_xor(v[2 * i],     d);
        float bb = v[2 * i + 1] + __shfl_xor(v[2 * i + 1], d);
        v[i] = (l & d) ? bb : a;
      }
    }
    float dsum = v[0];
    dsum += __shfl_xor(dsum, 16);
    dsum += __shfl_xor(dsum, 32);

    // ---- finalize: fast tanh + pack half2 + agent store (chain-major) ----
    {
      float rv = fast_tanh(dsum + pin);      // lane l: value for pair l&15
      float rvo = __shfl_xor(rv, 4);         // partner row (r^1), same chain
      if (l < 16 && ((l >> 2) & 1) == 0) {   // r even: pack (row r, row r+1)
        const int r = l >> 2, c = l & 3;
        UH2 hp; hp.h = __builtin_amdgcn_cvt_pkrtz(rv, rvo);
        const int pair = 16 * m + 2 * w + (r >> 1);
        ATSU(rbuf_h + (size_t)par * NB * (NR / 2)
                    + (size_t)(4 * g + c) * (NR / 2) + pair, hp.u);
      }
    }

    // ---- arrive (early): __syncthreads drains vmcnt(0) first ----
    __syncthreads();
    if (tid == 0) ATAU(bcp, 1u);

    // ---- shadow work while the group converges ----
    if (t + 1 < NS && tid < 256) {
      const int c = tid >> 6, ii = tid & 63;
      x_lds[(t + 1) % 3][c][ii] = x[((size_t)(4 * g + c) * NS + (t + 1)) * NI + ii];
    }
    if (t > 0 && m == ((t - 1) & 31)) {   // rotating local output reduction
      const int grp = tid >> 4;   // 0..31 -> (c,o)
      const int j   = tid & 15;
      const int c   = grp >> 3, o = grp & 7;
      float s = 0.f;
      #pragma unroll
      for (int k = 0; k < 16; ++k) {
        uint2 rr = *(const uint2*)&r_h[c][32 * k + 2 * j];
        uint2 ww = *(const uint2*)&woutr_h[o][32 * k + 2 * j];
        s = __builtin_amdgcn_fdot2(u2h(rr.x), u2h(ww.x), s, false);
        s = __builtin_amdgcn_fdot2(u2h(rr.y), u2h(ww.y), s, false);
      }
      #pragma unroll
      for (int e = 0; e < 4; ++e)
        s = fmaf(woutx_s[o][4 * j + e], x_lds[(t + 2) % 3][c][4 * j + e], s);
      s += __shfl_xor(s, 1); s += __shfl_xor(s, 2);
      s += __shfl_xor(s, 4); s += __shfl_xor(s, 8);
      if (j == 0) out[((size_t)(4 * g + c) * NS + (t - 1)) * NO + o] = s;
    }

    // ---- wait (late): single lane polls 4 lines (proven form) ----
    if (tid == 0) {
      const unsigned tg = 8u * (unsigned)(t + 1);
      for (;;) {
        unsigned u0 = ATLU(pol);
        unsigned u1 = ATLU(pol + 64);
        unsigned u2 = ATLU(pol + 128);
        unsigned u3 = ATLU(pol + 192);
        if (u0 >= tg && u1 >= tg && u2 >= tg && u3 >= tg) break;
      }
    }
    __syncthreads();
  }

  // ---- final output row t = NS-1 (one WG per group; r from rbuf_h) ----
  if (m == 31) {
    const int fpar = (NS - 1) & 1;
    const unsigned* rq = rbuf_h + (size_t)fpar * NB * (NR / 2)
                                + (size_t)(4 * g) * (NR / 2);
    r_h[0][tid] = ATLU(rq + tid);
    r_h[1][tid] = ATLU(rq + 512 + tid);
    r_h[2][tid] = ATLU(rq + 1024 + tid);
    r_h[3][tid] = ATLU(rq + 1536 + tid);
    __syncthreads();
    const int grp = tid >> 4;
    const int j   = tid & 15;
    const int c   = grp >> 3, o = grp & 7;
    float s = 0.f;
    #pragma unroll
    for (int k = 0; k < 16; ++k) {
      uint2 rr = *(const uint2*)&r_h[c][32 * k + 2 * j];
      uint2 ww = *(const uint2*)&woutr_h[o][32 * k + 2 * j];
      s = __builtin_amdgcn_fdot2(u2h(rr.x), u2h(ww.x), s, false);
      s = __builtin_amdgcn_fdot2(u2h(rr.y), u2h(ww.y), s, false);
    }
    #pragma unroll
    for (int e = 0; e < 4; ++e)
      s = fmaf(woutx_s[o][4 * j + e], x_lds[(NS - 1) % 3][c][4 * j + e], s);
    s += __shfl_xor(s, 1); s += __shfl_xor(s, 2);
    s += __shfl_xor(s, 4); s += __shfl_xor(s, 8);
    if (j == 0) out[((size_t)(4 * g + c) * NS + (NS - 1)) * NO + o] = s;
  }
}

extern "C" void kernel_launch(void* const* d_in, const int* in_sizes, int n_in,
                              void* d_out, int out_size, void* d_ws, size_t ws_size,
                              hipStream_t stream) {
  const float* x    = (const float*)d_in[0];
  const float* Win  = (const float*)d_in[1];
  const float* Wres = (const float*)d_in[2];
  const float* Wout = (const float*)d_in[3];
  float* out = (float*)d_out;

  char* ws = (char*)d_ws;
  unsigned int* cnt = (unsigned int*)ws;          // 8 KB: 8 groups x 4 lines
  unsigned int* rbuf_h = (unsigned int*)(ws + 8192);  // 2*32*512*4 = 128 KB

  hipLaunchKernelGGL(init_cnt_kernel, dim3(1), dim3(1024), 0, stream, cnt);
  hipLaunchKernelGGL(esn_scan, dim3(256), dim3(NT), 64 * 1024, stream,
                     x, Win, Wres, Wout, out, cnt, rbuf_h);
}